// Round 6
// baseline (123.581 us; speedup 1.0000x reference)
//
#include <hip/hip_runtime.h>
#include <hip/hip_cooperative_groups.h>

namespace cg = cooperative_groups;

// Chamfer distance v8: B=4, N=M=4096, D=3, fp32 in, scalar fp32 out.
//
// Accounting after R7 (67.99 us, absmax 0.0):
//   ~40 us poison fill (harness, fixed) + ~15-20 us restore dispatches
//   (harness, fixed) + pass ~7 us (VALU floor 6.0: 3 fma + 0.5 min3/pair,
//   no fp32 MFMA exists) + final ~1.5 us + ~1.5 us dispatch gap.
// Only controllable lever left: dispatch count (measured ~2 us/dispatch
// from R4->R5/R6 and R6->R7 deltas).
//
// R8 = single cooperative kernel. 512 blocks x 512 thr x 64 KB LDS =
// exactly 2 blocks/CU on 256 CUs -> co-resident, grid.sync() legal.
// Block 0 then runs the SAME 256-thread reduction as R7's chamfer_final
// (identical order -> bit-identical result). Partials cross XCDs via
// device-scope release/acquire atomics. Fallback to the 2-kernel R7 path
// if cooperative enqueue is rejected.
//
// Predicted: 68.0 -> ~65 us. If delta <1 us: dispatch margin exhausted,
// declare roofline next round.

#define NPTS 4096
#define TILE 64     // held points per block
#define G    8      // held points per wave (broadcast across 64 lanes)

__device__ __forceinline__ void chamfer_body(
    const float* __restrict__ coord, const float* __restrict__ gt,
    float* __restrict__ partials, int bx, int tid, float4* sc)
{
    int pass = bx >> 8;            // 0: held=gt/stream=coord, 1: reverse
    int r    = bx & 255;
    int b    = r >> 6;
    int tile = r & 63;             // 64 tiles of 64 held pts

    const float* hbase = (pass ? coord : gt) + b * NPTS * 3;
    const float* sbase = (pass ? gt : coord) + b * NPTS * 3;

    int wv  = tid >> 6;            // 0..7: wave id
    int ph  = tid & 63;            // lane

    // ---- stage raw stream -> packed LDS (x,y,z,|c|^2) ----
#pragma unroll
    for (int rr = 0; rr < 8; ++rr) {
        int p = rr * 512 + tid;
        const float* s0 = sbase + p * 3;
        float x = s0[0], y = s0[1], z = s0[2];
        sc[p] = make_float4(x, y, z, fmaf(x, x, fmaf(y, y, z * z)));
    }

    // ---- held points -> registers, folded as (-2x,-2y,-2z), |h|^2 ----
    float hx[G], hy[G], hz[G], h2[G], mn[G];
    int h0 = tile * TILE + wv * G;
#pragma unroll
    for (int g = 0; g < G; ++g) {
        const float* hp = hbase + (h0 + g) * 3;
        float x = hp[0], y = hp[1], z = hp[2];
        hx[g] = -2.f * x;
        hy[g] = -2.f * y;
        hz[g] = -2.f * z;
        h2[g] = fmaf(x, x, fmaf(y, y, z * z));
        mn[g] = INFINITY;
    }
    __syncthreads();               // stream fully staged; the only hot barrier

    // ---- all 4096 stream pts from LDS, 2 per lane per iter ----
#pragma unroll 8
    for (int it = 0; it < 32; ++it) {
        float4 c0 = sc[it * 128 + ph];
        float4 c1 = sc[it * 128 + 64 + ph];
#pragma unroll
        for (int g = 0; g < G; ++g) {
            float a = fmaf(c0.x, hx[g], c0.w);   // |c|^2 - 2 c.h
            a = fmaf(c0.y, hy[g], a);
            a = fmaf(c0.z, hz[g], a);
            float d = fmaf(c1.x, hx[g], c1.w);
            d = fmaf(c1.y, hy[g], d);
            d = fmaf(c1.z, hz[g], d);
            mn[g] = fminf(fminf(a, d), mn[g]);   // v_min3_f32
        }
    }

    // ---- min over 64 lanes, add |h|^2, sum over g ----
    float ssum = 0.f;
#pragma unroll
    for (int g = 0; g < G; ++g) {
        float v = mn[g];
        v = fminf(v, __shfl_xor(v, 32));
        v = fminf(v, __shfl_xor(v, 16));
        v = fminf(v, __shfl_xor(v, 8));
        v = fminf(v, __shfl_xor(v, 4));
        v = fminf(v, __shfl_xor(v, 2));
        v = fminf(v, __shfl_xor(v, 1));
        ssum += fmaxf(v + h2[g], 0.f);   // true d^2 >= 0; clamp fp cancellation
    }

    // block reduce: reuse sc (all reads done; barrier orders it)
    __syncthreads();
    float* red = (float*)sc;
    if (ph == 0) red[wv] = ssum;
    __syncthreads();
    if (tid == 0) {
        float t = 0.f;
#pragma unroll
        for (int k = 0; k < 8; ++k) t += red[k];
        __hip_atomic_store(&partials[bx], t, __ATOMIC_RELEASE,
                           __HIP_MEMORY_SCOPE_AGENT);
    }
}

__device__ __forceinline__ void final_reduce(
    const float* __restrict__ partials, float* __restrict__ out,
    int tid, float* wsum)
{
    // Identical structure/order to R7's chamfer_final (bit-exact result).
    if (tid < 256) {
        float s = __hip_atomic_load(&partials[tid], __ATOMIC_ACQUIRE,
                                    __HIP_MEMORY_SCOPE_AGENT)
                + __hip_atomic_load(&partials[tid + 256], __ATOMIC_ACQUIRE,
                                    __HIP_MEMORY_SCOPE_AGENT);
#pragma unroll
        for (int off = 32; off > 0; off >>= 1)
            s += __shfl_down(s, off);
        if ((tid & 63) == 0) wsum[tid >> 6] = s;
    }
    __syncthreads();
    if (tid == 0)
        out[0] = (wsum[0] + wsum[1] + wsum[2] + wsum[3]) * (1.0f / 16384.0f);
}

__global__ __launch_bounds__(512, 4) void chamfer_all(
    const float* __restrict__ coord, const float* __restrict__ gt,
    float* __restrict__ partials, float* __restrict__ out)
{
    __shared__ float4 sc[NPTS];    // 64 KB; reused for reductions
    int bx  = blockIdx.x;
    int tid = threadIdx.x;

    chamfer_body(coord, gt, partials, bx, tid, sc);

    cg::this_grid().sync();

    if (bx == 0) {
        __syncthreads();           // re-purpose sc for wsum
        final_reduce(partials, out, tid, (float*)sc);
    }
}

// ---- fallback 2-kernel path (used only if cooperative enqueue fails) ----
__global__ __launch_bounds__(512, 4) void chamfer_pass(
    const float* __restrict__ coord, const float* __restrict__ gt,
    float* __restrict__ partials)
{
    __shared__ float4 sc[NPTS];
    chamfer_body(coord, gt, partials, blockIdx.x, threadIdx.x, sc);
}

__global__ __launch_bounds__(256) void chamfer_final(
    const float* __restrict__ partials, float* __restrict__ out)
{
    __shared__ float wsum[4];
    final_reduce(partials, out, threadIdx.x, wsum);
}

extern "C" void kernel_launch(void* const* d_in, const int* in_sizes, int n_in,
                              void* d_out, int out_size, void* d_ws, size_t ws_size,
                              hipStream_t stream) {
    const float* coord = (const float*)d_in[0];  // [4,4096,3]
    const float* gt    = (const float*)d_in[1];  // [4,4096,3]
    float* partials = (float*)d_ws;              // 512 floats
    float* out      = (float*)d_out;

    void* args[] = {(void*)&coord, (void*)&gt, (void*)&partials, (void*)&out};
    hipError_t e = hipLaunchCooperativeKernel((const void*)chamfer_all,
                                              dim3(512), dim3(512),
                                              args, 0u, stream);
    if (e != hipSuccess) {
        chamfer_pass<<<512, 512, 0, stream>>>(coord, gt, partials);
        chamfer_final<<<1, 256, 0, stream>>>(partials, out);
    }
}

// Round 7
// 70.074 us; speedup vs baseline: 1.7636x; 1.7636x over previous
//
#include <hip/hip_runtime.h>

// Chamfer distance v9: B=4, N=M=4096, D=3, fp32 in, scalar fp32 out.
//
// History: R7 (2 dispatches) = 67.99 us. R8 (cooperative grid.sync fusion)
// = 123.6 us — grid.sync itself cost ~60 us (chamfer_all measured 67 us/
// dispatch vs ~7-8 us pass body). Lesson: only block 0 needs to wait;
// grid-wide sync is the wrong instrument.
//
// R9 = single dispatch with LAST-BLOCK detection that is poison-proof:
//   each block stores partials[bx] (relaxed) then pcomp[bx] = ~bits(partial)
//   (release). Block 0 spins until pcomp[i] == ~bits(partials[i]).
//   - uniform poison P can't match (~P != P);
//   - release order ⇒ any accepted pair yields the TRUE partial bits
//     (comp-new ⇒ val-new; remaining match cases force val_old==val_new).
//   Other 511 blocks exit immediately -> no deadlock at any occupancy;
//   bounded spin as a hang failsafe.
// Final reduction replicates R7's chamfer_final order exactly (bit-exact,
// absmax 0.0 expected).
//
// Predicted: 68.0 -> ~65-66 us (save final dispatch + gap). If >=67.5:
// margin exhausted -> revert to R7 & declare roofline.

#define NPTS 4096
#define TILE 64     // held points per block
#define G    8      // held points per wave (broadcast across 64 lanes)

__global__ __launch_bounds__(512, 4) void chamfer_fused(
    const float* __restrict__ coord, const float* __restrict__ gt,
    float* __restrict__ partials, unsigned int* __restrict__ pcomp,
    float* __restrict__ out)
{
    __shared__ float4 sc[NPTS];    // 64 KB; reused for reductions

    int bx   = blockIdx.x;
    int pass = bx >> 8;            // 0: held=gt/stream=coord, 1: reverse
    int r    = bx & 255;
    int b    = r >> 6;
    int tile = r & 63;             // 64 tiles of 64 held pts

    const float* hbase = (pass ? coord : gt) + b * NPTS * 3;
    const float* sbase = (pass ? gt : coord) + b * NPTS * 3;

    int tid = threadIdx.x;
    int wv  = tid >> 6;            // 0..7: wave id
    int ph  = tid & 63;            // lane

    // ---- stage raw stream -> packed LDS (x,y,z,|c|^2) ----
#pragma unroll
    for (int rr = 0; rr < 8; ++rr) {
        int p = rr * 512 + tid;
        const float* s0 = sbase + p * 3;
        float x = s0[0], y = s0[1], z = s0[2];
        sc[p] = make_float4(x, y, z, fmaf(x, x, fmaf(y, y, z * z)));
    }

    // ---- held points -> registers, folded as (-2x,-2y,-2z), |h|^2 ----
    // d^2 = h2 + (c.w + c.x*(-2hx) + c.y*(-2hy) + c.z*(-2hz))
    float hx[G], hy[G], hz[G], h2[G], mn[G];
    int h0 = tile * TILE + wv * G;
#pragma unroll
    for (int g = 0; g < G; ++g) {
        const float* hp = hbase + (h0 + g) * 3;
        float x = hp[0], y = hp[1], z = hp[2];
        hx[g] = -2.f * x;
        hy[g] = -2.f * y;
        hz[g] = -2.f * z;
        h2[g] = fmaf(x, x, fmaf(y, y, z * z));
        mn[g] = INFINITY;
    }
    __syncthreads();               // stream fully staged; the only hot barrier

    // ---- all 4096 stream pts from LDS, 2 per lane per iter ----
#pragma unroll 8
    for (int it = 0; it < 32; ++it) {
        float4 c0 = sc[it * 128 + ph];
        float4 c1 = sc[it * 128 + 64 + ph];
#pragma unroll
        for (int g = 0; g < G; ++g) {
            float a = fmaf(c0.x, hx[g], c0.w);   // |c|^2 - 2 c.h
            a = fmaf(c0.y, hy[g], a);
            a = fmaf(c0.z, hz[g], a);
            float d = fmaf(c1.x, hx[g], c1.w);
            d = fmaf(c1.y, hy[g], d);
            d = fmaf(c1.z, hz[g], d);
            mn[g] = fminf(fminf(a, d), mn[g]);   // v_min3_f32
        }
    }

    // ---- min over 64 lanes, add |h|^2, sum over g ----
    float ssum = 0.f;
#pragma unroll
    for (int g = 0; g < G; ++g) {
        float v = mn[g];
        v = fminf(v, __shfl_xor(v, 32));
        v = fminf(v, __shfl_xor(v, 16));
        v = fminf(v, __shfl_xor(v, 8));
        v = fminf(v, __shfl_xor(v, 4));
        v = fminf(v, __shfl_xor(v, 2));
        v = fminf(v, __shfl_xor(v, 1));
        ssum += fmaxf(v + h2[g], 0.f);   // true d^2 >= 0; clamp fp cancellation
    }

    // block reduce: reuse sc (all reads done; barrier orders it)
    __syncthreads();
    float* red = (float*)sc;
    if (ph == 0) red[wv] = ssum;
    __syncthreads();
    if (tid == 0) {
        float t = 0.f;
#pragma unroll
        for (int k = 0; k < 8; ++k) t += red[k];
        // value (relaxed) then complement (release): comp visible => val visible
        __hip_atomic_store((unsigned int*)&partials[bx], __float_as_uint(t),
                           __ATOMIC_RELAXED, __HIP_MEMORY_SCOPE_AGENT);
        __hip_atomic_store(&pcomp[bx], ~__float_as_uint(t),
                           __ATOMIC_RELEASE, __HIP_MEMORY_SCOPE_AGENT);
    }

    if (bx != 0) return;           // 511 blocks exit; only block 0 waits

    // ---- block 0: wait for all partials (poison-proof pair check) ----
    __syncthreads();               // tid0's stores issued; sc free for reuse
    unsigned int u;
    int iters = 0;
    for (;;) {
        u = __hip_atomic_load((const unsigned int*)&partials[tid],
                              __ATOMIC_ACQUIRE, __HIP_MEMORY_SCOPE_AGENT);
        unsigned int c = __hip_atomic_load(&pcomp[tid],
                              __ATOMIC_ACQUIRE, __HIP_MEMORY_SCOPE_AGENT);
        if (c == ~u) break;        // acceptance => u is the true partial bits
        if (++iters > (1 << 26)) break;   // failsafe vs hang (never expected)
        __builtin_amdgcn_s_sleep(1);
    }
    red[tid] = __uint_as_float(u); // 512 validated partials -> LDS
    __syncthreads();

    // ---- identical structure/order to R7's chamfer_final (bit-exact) ----
    if (tid < 256) {
        float s = red[tid] + red[tid + 256];
#pragma unroll
        for (int off = 32; off > 0; off >>= 1)
            s += __shfl_down(s, off);
        if ((tid & 63) == 0) red[512 + (tid >> 6)] = s;
    }
    __syncthreads();
    if (tid == 0)
        out[0] = (red[512] + red[513] + red[514] + red[515]) * (1.0f / 16384.0f);
}

extern "C" void kernel_launch(void* const* d_in, const int* in_sizes, int n_in,
                              void* d_out, int out_size, void* d_ws, size_t ws_size,
                              hipStream_t stream) {
    const float* coord = (const float*)d_in[0];  // [4,4096,3]
    const float* gt    = (const float*)d_in[1];  // [4,4096,3]
    float*        partials = (float*)d_ws;                       // 512 floats
    unsigned int* pcomp    = (unsigned int*)((char*)d_ws + 2048); // 512 words
    float*        out      = (float*)d_out;

    chamfer_fused<<<512, 512, 0, stream>>>(coord, gt, partials, pcomp, out);
}

// Round 8
// 69.067 us; speedup vs baseline: 1.7893x; 1.0146x over previous
//
#include <hip/hip_runtime.h>

// Chamfer distance v7 (REVERT to best-measured after R8/R9 fusion attempts).
// B=4, N=M=4096, D=3, fp32 in, scalar fp32 out.
//
// Dispatch-structure search, all measured:
//   3 dispatches (R6)            = 72.6 us
//   2 dispatches (R7, THIS)      = 68.0 us   <-- optimum
//   1 dispatch + spin-wait (R9)  = 70.1 us  (block0 cross-XCD polling tax)
//   1 dispatch + grid.sync (R8)  = 123.6 us (ROCm grid sync ~60 us)
// Window accounting at 68.0: ~40 us harness poison fill (256 MB, 84% HBM
// peak, untouchable) + ~18-20 us harness restore dispatches + pass ~7 us
// (VALU floor 6.0: 3 fma + 0.5 v_min3 per pair, 134.2M pairs, no fp32
// MFMA on CDNA4) + final ~1.5 us + ~1.5 us gap. Controllable headroom
// <= ~2 us == noise -> roofline.
//
// Pass kernel: fused pack+compute. Each block stages the raw stream cloud
// (48 KB, L2-resident) into packed LDS float4 (x,y,z,|c|^2), stride-512
// lane-contiguous ds_write_b128 (conflict-free); 8 waves hold 64 pts in
// registers folded as (-2x,-2y,-2z,|h|^2); one barrier; inner loop is
// 3 fma + v_min3 per 2 stream pts from ds_read_b128.

#define NPTS 4096
#define TILE 64     // held points per block
#define G    8      // held points per wave (broadcast across 64 lanes)

__global__ __launch_bounds__(512, 4) void chamfer_pass(
    const float* __restrict__ coord, const float* __restrict__ gt,
    float* __restrict__ partials)
{
    __shared__ float4 sc[NPTS];    // exactly 64 KB; reused for block-sum at end

    int bx   = blockIdx.x;
    int pass = bx >> 8;            // 0: held=gt/stream=coord, 1: reverse
    int r    = bx & 255;
    int b    = r >> 6;
    int tile = r & 63;             // 64 tiles of 64 held pts

    const float* hbase = (pass ? coord : gt) + b * NPTS * 3;
    const float* sbase = (pass ? gt : coord) + b * NPTS * 3;

    int tid = threadIdx.x;
    int wv  = tid >> 6;            // 0..7: wave id
    int ph  = tid & 63;            // lane

    // ---- stage raw stream -> packed LDS (x,y,z,|c|^2) ----
    // stride-512 interleave: lane-contiguous ds_write_b128, conflict-free.
#pragma unroll
    for (int rr = 0; rr < 8; ++rr) {
        int p = rr * 512 + tid;
        const float* s0 = sbase + p * 3;
        float x = s0[0], y = s0[1], z = s0[2];
        sc[p] = make_float4(x, y, z, fmaf(x, x, fmaf(y, y, z * z)));
    }

    // ---- held points -> registers, folded as (-2x,-2y,-2z), |h|^2 ----
    // d^2 = h2 + (c.w + c.x*(-2hx) + c.y*(-2hy) + c.z*(-2hz))
    float hx[G], hy[G], hz[G], h2[G], mn[G];
    int h0 = tile * TILE + wv * G;
#pragma unroll
    for (int g = 0; g < G; ++g) {
        const float* hp = hbase + (h0 + g) * 3;
        float x = hp[0], y = hp[1], z = hp[2];
        hx[g] = -2.f * x;
        hy[g] = -2.f * y;
        hz[g] = -2.f * z;
        h2[g] = fmaf(x, x, fmaf(y, y, z * z));   // same formula as pack: bit-exact
        mn[g] = INFINITY;
    }
    __syncthreads();               // stream fully staged; the only hot barrier

    // ---- all 4096 stream pts from LDS, 2 per lane per iter ----
#pragma unroll 8
    for (int it = 0; it < 32; ++it) {
        float4 c0 = sc[it * 128 + ph];
        float4 c1 = sc[it * 128 + 64 + ph];
#pragma unroll
        for (int g = 0; g < G; ++g) {
            float a = fmaf(c0.x, hx[g], c0.w);   // |c|^2 - 2 c.h
            a = fmaf(c0.y, hy[g], a);
            a = fmaf(c0.z, hz[g], a);
            float d = fmaf(c1.x, hx[g], c1.w);
            d = fmaf(c1.y, hy[g], d);
            d = fmaf(c1.z, hz[g], d);
            mn[g] = fminf(fminf(a, d), mn[g]);   // v_min3_f32
        }
    }

    // ---- min over 64 lanes, add |h|^2, sum over g ----
    float ssum = 0.f;
#pragma unroll
    for (int g = 0; g < G; ++g) {
        float v = mn[g];
        v = fminf(v, __shfl_xor(v, 32));
        v = fminf(v, __shfl_xor(v, 16));
        v = fminf(v, __shfl_xor(v, 8));
        v = fminf(v, __shfl_xor(v, 4));
        v = fminf(v, __shfl_xor(v, 2));
        v = fminf(v, __shfl_xor(v, 1));
        ssum += fmaxf(v + h2[g], 0.f);   // true d^2 >= 0; clamp fp cancellation
    }

    // block reduce: reuse sc (all reads done; barrier orders it)
    __syncthreads();
    float* red = (float*)sc;
    if (ph == 0) red[wv] = ssum;
    __syncthreads();
    if (tid == 0) {
        float t = 0.f;
#pragma unroll
        for (int k = 0; k < 8; ++k) t += red[k];
        partials[bx] = t;
    }
}

__global__ __launch_bounds__(256) void chamfer_final(
    const float* __restrict__ partials, float* __restrict__ out)
{
    __shared__ float wsum[4];
    int tid = threadIdx.x;
    float s = partials[tid] + partials[tid + 256];
#pragma unroll
    for (int off = 32; off > 0; off >>= 1)
        s += __shfl_down(s, off);
    if ((tid & 63) == 0) wsum[tid >> 6] = s;
    __syncthreads();
    if (tid == 0)
        out[0] = (wsum[0] + wsum[1] + wsum[2] + wsum[3]) * (1.0f / 16384.0f);
}

extern "C" void kernel_launch(void* const* d_in, const int* in_sizes, int n_in,
                              void* d_out, int out_size, void* d_ws, size_t ws_size,
                              hipStream_t stream) {
    const float* coord = (const float*)d_in[0];  // [4,4096,3]
    const float* gt    = (const float*)d_in[1];  // [4,4096,3]
    float* partials = (float*)d_ws;              // 512 floats
    float* out      = (float*)d_out;

    chamfer_pass<<<512, 512, 0, stream>>>(coord, gt, partials);
    chamfer_final<<<1, 256, 0, stream>>>(partials, out);
}